// Round 3
// baseline (2307.222 us; speedup 1.0000x reference)
//
#include <hip/hip_runtime.h>
#include <hip/hip_bf16.h>

// Problem dims
#define B_ 128
#define T_ 256
#define F_ 512
#define U_ 1024

typedef __attribute__((ext_vector_type(8))) short short8;   // 8 bf16 MFMA A/B frag (4 VGPRs)
typedef __attribute__((ext_vector_type(4))) float f32x4;    // 16x16 MFMA C/D frag
typedef __attribute__((ext_vector_type(16))) float f32x16;  // 32x32 MFMA C/D frag
typedef unsigned long long u64;

// Workspace layout (~7.1 MB):
//   [0, 2048)          : barrier counters (cnt[g] at int offset 256 + g*32)
//   [2048, +512KB)     : s_hi[8 group][2 parity][16384] bf16 frag-layout
//   [+512KB)           : s_lo  (same shape)
//   [+2MB)             : wsWh[1024x1024] bf16, B-frag layout (see winit)
//   [+2MB)             : wsWl
//   [+1MB)             : rsh[512x1024] bf16, 32x32 B-frag layout (see rinit)
//   [+1MB)             : rsl

#define SB_REGION 16384   // shorts per (group,parity) state region

// ---------------------------------------------------------------------------
// Kernel 0a: zero barrier counters; prefill parity-1 state with split(x0).
// ---------------------------------------------------------------------------
__global__ __launch_bounds__(256) void init_kernel(
    const float* __restrict__ x0, short* __restrict__ shi,
    short* __restrict__ slo, int* __restrict__ wsbar) {
  const int tid = threadIdx.x;
  if (blockIdx.x == 0) { wsbar[tid] = 0; wsbar[tid + 256] = 0; }
  const int idx = blockIdx.x * 256 + tid;   // 0..131071 = 8g * 16row * 1024k
  const int k   = idx & 1023;
  const int row = (idx >> 10) & 15;
  const int g   = idx >> 14;
  const float x = x0[k];
  const unsigned ux = __float_as_uint(x);
  const unsigned h  = ux & 0xFFFF0000u;
  const float l     = x - __uint_as_float(h);
  const size_t sidx = (size_t)(g * 2 + 1) * SB_REGION + ((size_t)(k >> 3) * 16 + row) * 8 + (k & 7);
  shi[sidx] = (short)(h >> 16);
  slo[sidx] = (short)(__float_as_uint(l) >> 16);
}

// ---------------------------------------------------------------------------
// Kernel 0b: pre-split W into bf16 hi/lo in B-frag layout (16x16x32 frags).
// Composite index (u>>4) = wave's 16-u column block; k = kh*512+ks*32+...
// ---------------------------------------------------------------------------
__global__ __launch_bounds__(256) void winit_kernel(
    const float* __restrict__ W, short* __restrict__ wsWh,
    short* __restrict__ wsWl) {
  const int idx = blockIdx.x * 256 + threadIdx.x;   // 0..1048575
  const int u = idx & 1023;
  const int k = idx >> 10;
  const float x = W[(size_t)k * U_ + u];
  const unsigned ux = __float_as_uint(x);
  const unsigned h  = ux & 0xFFFF0000u;
  const float l     = x - __uint_as_float(h);
  const int cu2 = u >> 4;                 // 0..63: 16-u column block
  const int kh = k >> 9, ks = (k >> 5) & 15;
  const int ln = (((k >> 3) & 3) << 4) | (u & 15);
  const size_t w = ((size_t)(((cu2 * 2 + kh) * 16 + ks)) * 64 + ln) * 8 + (k & 7);
  wsWh[w] = (short)(h >> 16);
  wsWl[w] = (short)(__float_as_uint(l) >> 16);
}

// ---------------------------------------------------------------------------
// Kernel 0c: pre-split R into bf16 hi/lo in 32x32x16 B-frag layout for hproj.
// ---------------------------------------------------------------------------
__global__ __launch_bounds__(256) void rinit_kernel(
    const float* __restrict__ R, short* __restrict__ rsh,
    short* __restrict__ rsl) {
  const int idx = blockIdx.x * 256 + threadIdx.x;   // 0..524287
  const int u = idx & 1023;
  const int k = idx >> 10;                          // 0..511
  const float x = R[(size_t)k * U_ + u];
  const unsigned ux = __float_as_uint(x);
  const unsigned h  = ux & 0xFFFF0000u;
  const float l     = x - __uint_as_float(h);
  const int ub = u >> 5;
  const int kt = k >> 4;
  const int ln = (((k >> 3) & 1) << 5) | (u & 31);
  const size_t w = ((size_t)(ub * 32 + kt) * 64 + ln) * 8 + (k & 7);
  rsh[w] = (short)(h >> 16);
  rsl[w] = (short)(__float_as_uint(l) >> 16);
}

// ---------------------------------------------------------------------------
// Kernel A: h[b,t,u] = inputs[b,t,:] @ R[:,u] + bias[u] -> out[(b*257+t)*1024+u]
// (unchanged — verified at ~4x the 16x16 version's speed.)
// ---------------------------------------------------------------------------
__global__ __launch_bounds__(256) void hproj_kernel(
    const float* __restrict__ inp, const short* __restrict__ rsh,
    const short* __restrict__ rsl, const float* __restrict__ bias,
    float* __restrict__ out) {
  __shared__ __align__(16) short bs[32 * 512];   // 32 chunks x 1KB = 32 KB

  const int tid  = threadIdx.x;
  const int wv   = tid >> 6, lane = tid & 63;
  const int mblk = blockIdx.x >> 2;    // 0..255 (128 rows each)
  const int nblk = blockIdx.x & 3;     // 0..3   (256 u each)
  const int row0 = mblk * 128 + wv * 32;
  const int arow = row0 + (lane & 31);
  const int asub = (lane >> 5) * 8;

  f32x16 c[8] = {};

  for (int kc = 0; kc < 16; ++kc) {
    __syncthreads();   // prior ds_reads complete before overwrite
#pragma unroll
    for (int i = 0; i < 8; ++i) {
      const int cidx = i * 4 + wv;         // 0..31
      const int a    = cidx >> 4;          // 0=hi, 1=lo
      const int ntc  = (cidx >> 1) & 7;
      const int ktl  = cidx & 1;
      const short* src = (a ? rsl : rsh) +
          ((size_t)((nblk * 8 + ntc) * 32 + kc * 2 + ktl) * 64 + lane) * 8;
      *(short8*)&bs[cidx * 512 + lane * 8] = *(const short8*)src;
    }
    __syncthreads();

    short8 ah[2], al[2];
#pragma unroll
    for (int kt = 0; kt < 2; ++kt) {
      const float* ap = inp + (size_t)arow * F_ + kc * 32 + kt * 16 + asub;
      float4 a0 = *(const float4*)ap;
      float4 a1 = *(const float4*)(ap + 4);
      float av[8] = {a0.x, a0.y, a0.z, a0.w, a1.x, a1.y, a1.z, a1.w};
#pragma unroll
      for (int j = 0; j < 8; ++j) {
        const unsigned ux = __float_as_uint(av[j]);
        const unsigned h  = ux & 0xFFFF0000u;
        const float l     = av[j] - __uint_as_float(h);
        ah[kt][j] = (short)(h >> 16);
        al[kt][j] = (short)(__float_as_uint(l) >> 16);
      }
    }

#pragma unroll
    for (int ntt = 0; ntt < 8; ++ntt) {
#pragma unroll
      for (int kt = 0; kt < 2; ++kt) {
        short8 bh = *(const short8*)&bs[((0 * 8 + ntt) * 2 + kt) * 512 + lane * 8];
        short8 bl = *(const short8*)&bs[((1 * 8 + ntt) * 2 + kt) * 512 + lane * 8];
        c[ntt] = __builtin_amdgcn_mfma_f32_32x32x16_bf16(ah[kt], bh, c[ntt], 0, 0, 0);
        c[ntt] = __builtin_amdgcn_mfma_f32_32x32x16_bf16(ah[kt], bl, c[ntt], 0, 0, 0);
        c[ntt] = __builtin_amdgcn_mfma_f32_32x32x16_bf16(al[kt], bh, c[ntt], 0, 0, 0);
      }
    }
  }

  const int crow0 = row0 + 4 * (lane >> 5);
  const int cu    = nblk * 256 + (lane & 31);
#pragma unroll
  for (int ntt = 0; ntt < 8; ++ntt) {
    const int u = cu + ntt * 32;
    const float bv = bias[u];
#pragma unroll
    for (int reg = 0; reg < 16; ++reg) {
      const int row = crow0 + (reg & 3) + 8 * (reg >> 2);   // b*256 + t
      const int b   = row >> 8;
      out[(size_t)(row + b) * U_ + u] = c[ntt][reg] + bv;
    }
  }
}

// ---------------------------------------------------------------------------
// Kernel B: persistent recurrence. Grid = 256 WGs x 128 thr (2 waves).
// CHANGES vs round 2:
//  (1) W frags PINNED in registers via opaque asm touch — rocprof showed
//      VGPR_Count=176 < the 256 VGPRs W needs, i.e. the compiler was
//      REMATERIALIZING the W loads from L2 inside the t-loop all along.
//  (2) 256 WGs (all CUs active; was 128): group g = blockIdx&7 has 32 WGs,
//      each WG = 2 waves x 16 u (full K). Per-CU LDS A-read halves.
//  (3) LDS padded >80KB so only 1 WG/CU can resident -> uniform placement.
// ---------------------------------------------------------------------------
__global__ __launch_bounds__(128, 1) void recur_kernel(
    const short* __restrict__ wsWh, const short* __restrict__ wsWl,
    float* __restrict__ out, int* __restrict__ wsbar,
    short* __restrict__ shi, short* __restrict__ slo) {
  __shared__ short lds_h[SB_REGION];      // 32 KB
  __shared__ short lds_l[SB_REGION];      // 32 KB
  __shared__ float sred[2 * 256];         // 2 KB: per-wave 16x16 transpose patch
  __shared__ int   lcnt;                  // wave arrival counter (monotone)
  __shared__ u64   lds_pad[2048];         // 16 KB: forces 1 WG/CU (>80KB total)

  const int tid  = threadIdx.x;
  const int nt   = tid >> 6, lane = tid & 63;   // nt in 0..1
  const int lm   = lane & 15, quad = lane >> 4;
  const int g    = blockIdx.x & 7;        // group (XCD co-located)
  const int cbb  = blockIdx.x >> 3;       // 0..31 (32-u block)
  const int u    = cbb * 32 + nt * 16 + lm;

  if (tid == 0) lcnt = 0;
  if ((int)blockDim.x == 1) lds_pad[tid] = 0;   // never true; defeats DCE

  // ---- one-time W fragment preload: 64 coalesced dwordx4 loads ----
  short8 wh[32], wl[32];
  {
    const int cu2 = cbb * 2 + nt;         // composite 16-u block id (u>>4)
#pragma unroll
    for (int ks = 0; ks < 32; ++ks) {
      const size_t a = ((((size_t)cu2 * 2 + (ks >> 4)) * 16 + (ks & 15)) * 64 + lane) * 8;
      wh[ks] = *(const short8*)(wsWh + a);
      wl[ks] = *(const short8*)(wsWl + a);
    }
  }
  // PIN: make frags asm-defined so the compiler cannot rematerialize the
  // loads inside the t-loop (forces true register residency).
#pragma unroll
  for (int ks = 0; ks < 32; ++ks) {
    asm volatile("" : "+v"(wh[ks]));
    asm volatile("" : "+v"(wl[ks]));
  }

  float accE[4] = {0.f, 0.f, 0.f, 0.f};
  int* const cntp = wsbar + 256 + g * 32;
  const size_t gbase = (size_t)g * 2 * SB_REGION;

  // pack mapping (wave-local): row rw = lane&15, u-quad u0q = (lane>>4)*4
  const int rw  = lane & 15;
  const int u0q = (lane >> 4) * 4;
  const int ug0 = cbb * 32 + nt * 16 + u0q;
  const size_t cs_dst = ((size_t)(ug0 >> 3) * 16 + rw) * 8 + (ug0 & 7); // 8B-aligned

  // ---- initial h prefetch (t = 0) ----
  float hv[4];
#pragma unroll
  for (int r = 0; r < 4; ++r) {
    const int row = g * 16 + quad * 4 + r;
    hv[r] = out[((size_t)row * 257 + 0) * U_ + u];
  }

  for (int t = 0; t < T_; ++t) {
    const int pr = (t + 1) & 1;        // parity holding s_{t-1}
    const int pw = t & 1;              // parity receiving s_t

    // ---- batched coherent load of s_{t-1} into regs, then LDS ----
    {
      const u64* gh = (const u64*)(shi + gbase + (size_t)pr * SB_REGION);
      const u64* gl = (const u64*)(slo + gbase + (size_t)pr * SB_REGION);
      u64* lh = (u64*)lds_h;
      u64* ll = (u64*)lds_l;
#pragma unroll
      for (int c = 0; c < 4; ++c) {
        u64 rg[8];
#pragma unroll
        for (int i = 0; i < 8; ++i)
          rg[i] = __hip_atomic_load(gh + (c * 8 + i) * 128 + tid,
                                    __ATOMIC_RELAXED, __HIP_MEMORY_SCOPE_AGENT);
#pragma unroll
        for (int i = 0; i < 8; ++i) lh[(c * 8 + i) * 128 + tid] = rg[i];
      }
#pragma unroll
      for (int c = 0; c < 4; ++c) {
        u64 rg[8];
#pragma unroll
        for (int i = 0; i < 8; ++i)
          rg[i] = __hip_atomic_load(gl + (c * 8 + i) * 128 + tid,
                                    __ATOMIC_RELAXED, __HIP_MEMORY_SCOPE_AGENT);
#pragma unroll
        for (int i = 0; i < 8; ++i) ll[(c * 8 + i) * 128 + tid] = rg[i];
      }
    }
    __syncthreads();   // S1: state staged

    // ---- 96 MFMA over FULL K: 6 independent chains ----
    f32x4 c0 = {0,0,0,0}, c1 = {0,0,0,0}, c2 = {0,0,0,0};
    f32x4 c3 = {0,0,0,0}, c4 = {0,0,0,0}, c5 = {0,0,0,0};
#pragma unroll
    for (int ks = 0; ks < 32; ks += 2) {
      const int off0 = ((ks * 4 + quad) * 16 + lm) * 8;
      const int off1 = (((ks + 1) * 4 + quad) * 16 + lm) * 8;
      short8 ah0 = *(const short8*)&lds_h[off0];
      short8 al0 = *(const short8*)&lds_l[off0];
      short8 ah1 = *(const short8*)&lds_h[off1];
      short8 al1 = *(const short8*)&lds_l[off1];
      c0 = __builtin_amdgcn_mfma_f32_16x16x32_bf16(ah0, wh[ks], c0, 0, 0, 0);
      c1 = __builtin_amdgcn_mfma_f32_16x16x32_bf16(ah0, wl[ks], c1, 0, 0, 0);
      c2 = __builtin_amdgcn_mfma_f32_16x16x32_bf16(al0, wh[ks], c2, 0, 0, 0);
      c3 = __builtin_amdgcn_mfma_f32_16x16x32_bf16(ah1, wh[ks + 1], c3, 0, 0, 0);
      c4 = __builtin_amdgcn_mfma_f32_16x16x32_bf16(ah1, wl[ks + 1], c4, 0, 0, 0);
      c5 = __builtin_amdgcn_mfma_f32_16x16x32_bf16(al1, wh[ks + 1], c5, 0, 0, 0);
    }
    f32x4 y = ((c0 + c3) + (c1 + c4)) + (c2 + c5);

    // ---- epilogue: s = tanh(h + y) ----
    float sv[4];
#pragma unroll
    for (int r = 0; r < 4; ++r) {
      sv[r] = tanhf(y[r] + hv[r]);
      accE[r] += __expf(sv[r]);
    }

    if (t != T_ - 1) {
      // ---- wave-local transpose: (4 rows x 1 u) -> (1 row x 4 consec u) ----
#pragma unroll
      for (int r = 0; r < 4; ++r)
        sred[nt * 256 + (quad * 4 + r) * 16 + lm] = sv[r];
      asm volatile("s_waitcnt lgkmcnt(0)" ::: "memory");
      __builtin_amdgcn_sched_barrier(0);
      float4 sq = *(const float4*)&sred[nt * 256 + rw * 16 + u0q];

      // ---- split + pack + ONE 8B coherent store per array ----
      float v[4] = {sq.x, sq.y, sq.z, sq.w};
      u64 ph = 0, pl = 0;
#pragma unroll
      for (int j = 0; j < 4; ++j) {
        const unsigned ux = __float_as_uint(v[j]);
        const unsigned h  = ux & 0xFFFF0000u;
        const float l     = v[j] - __uint_as_float(h);
        ph |= (u64)(unsigned short)(h >> 16) << (16 * j);
        pl |= (u64)(unsigned short)(__float_as_uint(l) >> 16) << (16 * j);
      }
      u64* dsth = (u64*)(shi + gbase + (size_t)pw * SB_REGION + cs_dst);
      u64* dstl = (u64*)(slo + gbase + (size_t)pw * SB_REGION + cs_dst);
      __hip_atomic_store(dsth, ph, __ATOMIC_RELAXED, __HIP_MEMORY_SCOPE_AGENT);
      __hip_atomic_store(dstl, pl, __ATOMIC_RELAXED, __HIP_MEMORY_SCOPE_AGENT);
      asm volatile("s_waitcnt vmcnt(0)" ::: "memory");   // drain own state stores
      if (lane == 0) {
        const int prev = atomicAdd(&lcnt, 1);
        if (prev == 2 * t + 1)   // last of this WG's 2 waves this step
          __hip_atomic_fetch_add(cntp, 1, __ATOMIC_RELAXED,
                                 __HIP_MEMORY_SCOPE_AGENT);
      }
    }

    // ---- out stores of s_t (off the critical path) ----
#pragma unroll
    for (int r = 0; r < 4; ++r) {
      const int row = g * 16 + quad * 4 + r;
      out[((size_t)row * 257 + t) * U_ + u] = sv[r];
    }

    if (t != T_ - 1) {
      // ---- prefetch h for t+1 during the barrier wait ----
#pragma unroll
      for (int r = 0; r < 4; ++r) {
        const int row = g * 16 + quad * 4 + r;
        hv[r] = out[((size_t)row * 257 + (t + 1)) * U_ + u];
      }
      // ---- single-poller group barrier (32 arrivals) ----
      if (tid == 0) {
        const int target = 32 * (t + 1);
        int vcnt = __hip_atomic_load(cntp, __ATOMIC_RELAXED,
                                     __HIP_MEMORY_SCOPE_AGENT);
        while (vcnt < target) {
          __builtin_amdgcn_s_sleep(1);
          vcnt = __hip_atomic_load(cntp, __ATOMIC_RELAXED,
                                   __HIP_MEMORY_SCOPE_AGENT);
        }
      }
      __syncthreads();   // S2: release (also protects LDS reuse at t+1)
    }
  }

  // terminal: out[b, 256, u] = log(tanh(mean_t exp(s_t)))   (beta = 1)
#pragma unroll
  for (int r = 0; r < 4; ++r) {
    const int row = g * 16 + quad * 4 + r;
    out[((size_t)row * 257 + T_) * U_ + u] = logf(tanhf(accE[r] * (1.0f / 256.0f)));
  }
}

extern "C" void kernel_launch(void* const* d_in, const int* in_sizes, int n_in,
                              void* d_out, int out_size, void* d_ws, size_t ws_size,
                              hipStream_t stream) {
  (void)in_sizes; (void)n_in; (void)out_size; (void)ws_size;
  const float* inp  = (const float*)d_in[0];
  const float* R    = (const float*)d_in[1];
  const float* W    = (const float*)d_in[2];
  const float* bias = (const float*)d_in[3];
  const float* x0   = (const float*)d_in[4];
  float* out = (float*)d_out;
  int*   wsbar = (int*)d_ws;
  short* shi  = (short*)((char*)d_ws + 2048);
  short* slo  = shi + 8 * 2 * SB_REGION;            // +512 KB
  short* wsWh = slo + 8 * 2 * SB_REGION;            // +512 KB
  short* wsWl = wsWh + 1024 * 1024;                 // +2 MB
  short* rsh  = wsWl + 1024 * 1024;                 // +2 MB
  short* rsl  = rsh + 512 * 1024;                   // +1 MB

  init_kernel<<<dim3(512), dim3(256), 0, stream>>>(x0, shi, slo, wsbar);
  winit_kernel<<<dim3(4096), dim3(256), 0, stream>>>(W, wsWh, wsWl);
  rinit_kernel<<<dim3(2048), dim3(256), 0, stream>>>(R, rsh, rsl);
  hproj_kernel<<<dim3(1024), dim3(256), 0, stream>>>(inp, rsh, rsl, bias, out);
  recur_kernel<<<dim3(256), dim3(128), 0, stream>>>(wsWh, wsWl, out, wsbar, shi, slo);
}

// Round 4
// 1230.443 us; speedup vs baseline: 1.8751x; 1.8751x over previous
//
#include <hip/hip_runtime.h>
#include <hip/hip_bf16.h>

// Problem dims
#define B_ 128
#define T_ 256
#define F_ 512
#define U_ 1024

typedef __attribute__((ext_vector_type(8))) short short8;   // 8 bf16 MFMA A/B frag (4 VGPRs)
typedef __attribute__((ext_vector_type(4))) float f32x4;    // 16x16 MFMA C/D frag
typedef __attribute__((ext_vector_type(16))) float f32x16;  // 32x32 MFMA C/D frag
typedef unsigned long long u64;

// Workspace layout (~7.1 MB):
//   [0, 2048)          : barrier counters (cnt[g] at int offset 256 + g*32)
//   [2048, +512KB)     : s_hi[8 group][2 parity][16384] bf16 frag-layout
//   [+512KB)           : s_lo  (same shape)
//   [+2MB)             : wsWh[1024x1024] bf16, B-frag layout (see winit)
//   [+2MB)             : wsWl
//   [+1MB)             : rsh[512x1024] bf16, 32x32 B-frag layout (see rinit)
//   [+1MB)             : rsl

#define SB_REGION 16384   // shorts per (group,parity) state region

// ---------------------------------------------------------------------------
// Kernel 0a: zero barrier counters; prefill parity-1 state with split(x0).
// ---------------------------------------------------------------------------
__global__ __launch_bounds__(256) void init_kernel(
    const float* __restrict__ x0, short* __restrict__ shi,
    short* __restrict__ slo, int* __restrict__ wsbar) {
  const int tid = threadIdx.x;
  if (blockIdx.x == 0) { wsbar[tid] = 0; wsbar[tid + 256] = 0; }
  const int idx = blockIdx.x * 256 + tid;   // 0..131071 = 8g * 16row * 1024k
  const int k   = idx & 1023;
  const int row = (idx >> 10) & 15;
  const int g   = idx >> 14;
  const float x = x0[k];
  const unsigned ux = __float_as_uint(x);
  const unsigned h  = ux & 0xFFFF0000u;
  const float l     = x - __uint_as_float(h);
  const size_t sidx = (size_t)(g * 2 + 1) * SB_REGION + ((size_t)(k >> 3) * 16 + row) * 8 + (k & 7);
  shi[sidx] = (short)(h >> 16);
  slo[sidx] = (short)(__float_as_uint(l) >> 16);
}

// ---------------------------------------------------------------------------
// Kernel 0b: pre-split W into bf16 hi/lo in B-frag layout (16x16x32 frags),
// round-0 verified layout. For wave (cb,nt,kh), frag ks, lane ln, elem j:
//   k = kh*512 + ks*32 + (ln>>4)*8 + j,  u = cb*64 + nt*16 + (ln&15)
// ---------------------------------------------------------------------------
__global__ __launch_bounds__(256) void winit_kernel(
    const float* __restrict__ W, short* __restrict__ wsWh,
    short* __restrict__ wsWl) {
  const int idx = blockIdx.x * 256 + threadIdx.x;   // 0..1048575
  const int u = idx & 1023;
  const int k = idx >> 10;
  const float x = W[(size_t)k * U_ + u];
  const unsigned ux = __float_as_uint(x);
  const unsigned h  = ux & 0xFFFF0000u;
  const float l     = x - __uint_as_float(h);
  const int cb = u >> 6, nt = (u >> 4) & 3;
  const int kh = k >> 9, ks = (k >> 5) & 15;
  const int ln = (((k >> 3) & 3) << 4) | (u & 15);
  const size_t w = ((size_t)((((cb * 4 + nt) * 2 + kh) * 16 + ks)) * 64 + ln) * 8 + (k & 7);
  wsWh[w] = (short)(h >> 16);
  wsWl[w] = (short)(__float_as_uint(l) >> 16);
}

// ---------------------------------------------------------------------------
// Kernel 0c: pre-split R into bf16 hi/lo in 32x32x16 B-frag layout for hproj
// (verified rounds 1-3).
// ---------------------------------------------------------------------------
__global__ __launch_bounds__(256) void rinit_kernel(
    const float* __restrict__ R, short* __restrict__ rsh,
    short* __restrict__ rsl) {
  const int idx = blockIdx.x * 256 + threadIdx.x;   // 0..524287
  const int u = idx & 1023;
  const int k = idx >> 10;                          // 0..511
  const float x = R[(size_t)k * U_ + u];
  const unsigned ux = __float_as_uint(x);
  const unsigned h  = ux & 0xFFFF0000u;
  const float l     = x - __uint_as_float(h);
  const int ub = u >> 5;
  const int kt = k >> 4;
  const int ln = (((k >> 3) & 1) << 5) | (u & 31);
  const size_t w = ((size_t)(ub * 32 + kt) * 64 + ln) * 8 + (k & 7);
  rsh[w] = (short)(h >> 16);
  rsl[w] = (short)(__float_as_uint(l) >> 16);
}

// ---------------------------------------------------------------------------
// Kernel A: h[b,t,u] = inputs[b,t,:] @ R[:,u] + bias[u] -> out[(b*257+t)*1024+u]
// 32x32x16 MFMA version (verified rounds 1-3, ~4x the 16x16 version).
// ---------------------------------------------------------------------------
__global__ __launch_bounds__(256) void hproj_kernel(
    const float* __restrict__ inp, const short* __restrict__ rsh,
    const short* __restrict__ rsl, const float* __restrict__ bias,
    float* __restrict__ out) {
  __shared__ __align__(16) short bs[32 * 512];   // 32 chunks x 1KB = 32 KB

  const int tid  = threadIdx.x;
  const int wv   = tid >> 6, lane = tid & 63;
  const int mblk = blockIdx.x >> 2;    // 0..255 (128 rows each)
  const int nblk = blockIdx.x & 3;     // 0..3   (256 u each)
  const int row0 = mblk * 128 + wv * 32;
  const int arow = row0 + (lane & 31);
  const int asub = (lane >> 5) * 8;

  f32x16 c[8] = {};

  for (int kc = 0; kc < 16; ++kc) {
    __syncthreads();   // prior ds_reads complete before overwrite
#pragma unroll
    for (int i = 0; i < 8; ++i) {
      const int cidx = i * 4 + wv;         // 0..31
      const int a    = cidx >> 4;          // 0=hi, 1=lo
      const int ntc  = (cidx >> 1) & 7;
      const int ktl  = cidx & 1;
      const short* src = (a ? rsl : rsh) +
          ((size_t)((nblk * 8 + ntc) * 32 + kc * 2 + ktl) * 64 + lane) * 8;
      *(short8*)&bs[cidx * 512 + lane * 8] = *(const short8*)src;
    }
    __syncthreads();

    short8 ah[2], al[2];
#pragma unroll
    for (int kt = 0; kt < 2; ++kt) {
      const float* ap = inp + (size_t)arow * F_ + kc * 32 + kt * 16 + asub;
      float4 a0 = *(const float4*)ap;
      float4 a1 = *(const float4*)(ap + 4);
      float av[8] = {a0.x, a0.y, a0.z, a0.w, a1.x, a1.y, a1.z, a1.w};
#pragma unroll
      for (int j = 0; j < 8; ++j) {
        const unsigned ux = __float_as_uint(av[j]);
        const unsigned h  = ux & 0xFFFF0000u;
        const float l     = av[j] - __uint_as_float(h);
        ah[kt][j] = (short)(h >> 16);
        al[kt][j] = (short)(__float_as_uint(l) >> 16);
      }
    }

#pragma unroll
    for (int ntt = 0; ntt < 8; ++ntt) {
#pragma unroll
      for (int kt = 0; kt < 2; ++kt) {
        short8 bh = *(const short8*)&bs[((0 * 8 + ntt) * 2 + kt) * 512 + lane * 8];
        short8 bl = *(const short8*)&bs[((1 * 8 + ntt) * 2 + kt) * 512 + lane * 8];
        c[ntt] = __builtin_amdgcn_mfma_f32_32x32x16_bf16(ah[kt], bh, c[ntt], 0, 0, 0);
        c[ntt] = __builtin_amdgcn_mfma_f32_32x32x16_bf16(ah[kt], bl, c[ntt], 0, 0, 0);
        c[ntt] = __builtin_amdgcn_mfma_f32_32x32x16_bf16(al[kt], bh, c[ntt], 0, 0, 0);
      }
    }
  }

  const int crow0 = row0 + 4 * (lane >> 5);
  const int cu    = nblk * 256 + (lane & 31);
#pragma unroll
  for (int ntt = 0; ntt < 8; ++ntt) {
    const int u = cu + ntt * 32;
    const float bv = bias[u];
#pragma unroll
    for (int reg = 0; reg < 16; ++reg) {
      const int row = crow0 + (reg & 3) + 8 * (reg >> 2);   // b*256 + t
      const int b   = row >> 8;
      out[(size_t)(row + b) * U_ + u] = c[ntt][reg] + bv;
    }
  }
}

// ---------------------------------------------------------------------------
// Kernel B: persistent recurrence — REVERTED to the verified 966-us inherited
// structure (128 WGs x 512 thr, 8 waves, kh-split, S1..S5 barriers, tid0-only
// poller). rocprof showed VGPR=100 there: W streams from L2 every step, and
// the 8-wave occupancy is what hides that latency — rounds 2-3 proved that
// reducing waves or forcing residency only regresses. Two micro-edits inside
// the unchanged sync skeleton:
//  (a) h prefetch for t+1 moved into the S3->S4 gap (kh0 waves idle there);
//  (b) 48-MFMA chain split into 3 independent accumulators (ILP only).
// ---------------------------------------------------------------------------
__global__ __launch_bounds__(512, 2) void recur_kernel(
    const short* __restrict__ wsWh, const short* __restrict__ wsWl,
    float* __restrict__ out, int* __restrict__ wsbar,
    short* __restrict__ shi, short* __restrict__ slo) {
  __shared__ short lds_h[SB_REGION];      // 32 KB
  __shared__ short lds_l[SB_REGION];      // 32 KB
  __shared__ float red[4 * 64 * 4];       // 4 KB  [nt][lane][4]
  __shared__ float sstage[16 * 64];       // 4 KB  [row][u64]

  const int tid  = threadIdx.x;
  const int wv   = tid >> 6, lane = tid & 63;
  const int lm   = lane & 15, quad = lane >> 4;
  const int nt   = wv & 3, kh = wv >> 2;
  const int g    = blockIdx.x & 7;        // group (XCD co-located)
  const int cb   = blockIdx.x >> 3;       // 0..15
  const int u    = cb * 64 + nt * 16 + lm;

  // ---- one-time W fragment preload: 32 coalesced dwordx4 loads ----
  short8 wh[16], wl[16];
  {
    const size_t wbase = ((size_t)(((cb * 4 + nt) * 2 + kh) * 16) * 64 + lane) * 8;
#pragma unroll
    for (int ks = 0; ks < 16; ++ks) {
      wh[ks] = *(const short8*)(wsWh + wbase + (size_t)ks * 512);
      wl[ks] = *(const short8*)(wsWl + wbase + (size_t)ks * 512);
    }
  }

  float accE[4] = {0.f, 0.f, 0.f, 0.f};
  int* const cntp = wsbar + 256 + g * 32;
  const size_t gbase = (size_t)g * 2 * SB_REGION;

  // pack mapping (kh==1 waves, local id pt = tid-256 in 0..255): 4 elems each
  const int pt     = tid & 255;
  const int cs_row = (pt * 4) >> 6;           // 0..15
  const int cs_ug  = cb * 64 + ((pt * 4) & 63);
  const size_t cs_dst = ((size_t)(cs_ug >> 3) * 16 + cs_row) * 8 + (cs_ug & 7); // 8B-aligned

  // ---- initial h load (t = 0), kh0 only ----
  float hv[4] = {0.f, 0.f, 0.f, 0.f};
  if (kh == 0) {
#pragma unroll
    for (int r = 0; r < 4; ++r) {
      const int row = g * 16 + quad * 4 + r;
      hv[r] = out[((size_t)row * 257 + 0) * U_ + u];
    }
  }

  for (int t = 0; t < T_; ++t) {
    const int pr = (t + 1) & 1;        // parity holding s_{t-1}
    const int pw = t & 1;              // parity receiving s_t

    // ---- batched coherent load of s_{t-1} into regs, then LDS ----
    {
      const u64* gh = (const u64*)(shi + gbase + (size_t)pr * SB_REGION);
      const u64* gl = (const u64*)(slo + gbase + (size_t)pr * SB_REGION);
      u64 rh[8], rl[8];
#pragma unroll
      for (int i = 0; i < 8; ++i)
        rh[i] = __hip_atomic_load(gh + i * 512 + tid, __ATOMIC_RELAXED,
                                  __HIP_MEMORY_SCOPE_AGENT);
#pragma unroll
      for (int i = 0; i < 8; ++i)
        rl[i] = __hip_atomic_load(gl + i * 512 + tid, __ATOMIC_RELAXED,
                                  __HIP_MEMORY_SCOPE_AGENT);
      u64* lh = (u64*)lds_h;
      u64* ll = (u64*)lds_l;
#pragma unroll
      for (int i = 0; i < 8; ++i) lh[i * 512 + tid] = rh[i];
#pragma unroll
      for (int i = 0; i < 8; ++i) ll[i * 512 + tid] = rl[i];
    }
    __syncthreads();   // S1: state staged

    // ---- 48 MFMA over this wave's K half: 3 independent chains ----
    f32x4 c0 = {0, 0, 0, 0}, c1 = {0, 0, 0, 0}, c2 = {0, 0, 0, 0};
#pragma unroll
    for (int ks = 0; ks < 16; ++ks) {
      const int off = (((kh * 16 + ks) * 4 + quad) * 16 + lm) * 8;
      short8 ah = *(const short8*)&lds_h[off];
      short8 al = *(const short8*)&lds_l[off];
      c0 = __builtin_amdgcn_mfma_f32_16x16x32_bf16(ah, wh[ks], c0, 0, 0, 0);
      c1 = __builtin_amdgcn_mfma_f32_16x16x32_bf16(ah, wl[ks], c1, 0, 0, 0);
      c2 = __builtin_amdgcn_mfma_f32_16x16x32_bf16(al, wh[ks], c2, 0, 0, 0);
    }
    f32x4 c = (c0 + c1) + c2;
    if (kh == 1) *(f32x4*)&red[(nt * 64 + lane) * 4] = c;
    __syncthreads();   // S2: red visible; all LDS state reads complete

    // ---- epilogue on kh0 waves: s = tanh(h + y); out store; stage s ----
    if (kh == 0) {
      f32x4 p = *(const f32x4*)&red[(nt * 64 + lane) * 4];
      c += p;
#pragma unroll
      for (int r = 0; r < 4; ++r) {
        const int row15 = quad * 4 + r;
        const int row   = g * 16 + row15;
        const float s   = tanhf(c[r] + hv[r]);
        out[((size_t)row * 257 + t) * U_ + u] = s;
        accE[r] += __expf(s);
        sstage[row15 * 64 + (nt * 16 + lm)] = s;
      }
    }
    __syncthreads();   // S3: sstage visible

    // ---- S3->S4 gap: kh1 packs/stores state; kh0 prefetches h for t+1 ----
    if (kh == 1) {
      float4 sv = *(const float4*)&sstage[pt * 4];
      float v[4] = {sv.x, sv.y, sv.z, sv.w};
      u64 ph = 0, pl = 0;
#pragma unroll
      for (int j = 0; j < 4; ++j) {
        const unsigned ux = __float_as_uint(v[j]);
        const unsigned h  = ux & 0xFFFF0000u;
        const float l     = v[j] - __uint_as_float(h);
        ph |= (u64)(unsigned short)(h >> 16) << (16 * j);
        pl |= (u64)(unsigned short)(__float_as_uint(l) >> 16) << (16 * j);
      }
      u64* dsth = (u64*)(shi + gbase + (size_t)pw * SB_REGION + cs_dst);
      u64* dstl = (u64*)(slo + gbase + (size_t)pw * SB_REGION + cs_dst);
      __hip_atomic_store(dsth, ph, __ATOMIC_RELAXED, __HIP_MEMORY_SCOPE_AGENT);
      __hip_atomic_store(dstl, pl, __ATOMIC_RELAXED, __HIP_MEMORY_SCOPE_AGENT);
    } else if (t != T_ - 1) {
#pragma unroll
      for (int r = 0; r < 4; ++r) {
        const int row = g * 16 + quad * 4 + r;
        hv[r] = out[((size_t)row * 257 + (t + 1)) * U_ + u];
      }
    }
    asm volatile("s_waitcnt vmcnt(0)" ::: "memory");
    __syncthreads();   // S4: all WG stores drained

    // ---- per-group barrier (16 WGs), relaxed monotone counter ----
    if (tid == 0) {
      const int prev = __hip_atomic_fetch_add(cntp, 1, __ATOMIC_RELAXED,
                                              __HIP_MEMORY_SCOPE_AGENT);
      const int target = 16 * (t + 1);
      if (prev != target - 1) {
        while (__hip_atomic_load(cntp, __ATOMIC_RELAXED,
                                 __HIP_MEMORY_SCOPE_AGENT) < target) {
          __builtin_amdgcn_s_sleep(1);
        }
      }
    }
    __syncthreads();   // S5: release
  }

  // terminal: out[b, 256, u] = log(tanh(mean_t exp(s_t)))   (beta = 1)
  if (kh == 0) {
#pragma unroll
    for (int r = 0; r < 4; ++r) {
      const int row = g * 16 + quad * 4 + r;
      out[((size_t)row * 257 + T_) * U_ + u] = logf(tanhf(accE[r] * (1.0f / 256.0f)));
    }
  }
}

extern "C" void kernel_launch(void* const* d_in, const int* in_sizes, int n_in,
                              void* d_out, int out_size, void* d_ws, size_t ws_size,
                              hipStream_t stream) {
  (void)in_sizes; (void)n_in; (void)out_size; (void)ws_size;
  const float* inp  = (const float*)d_in[0];
  const float* R    = (const float*)d_in[1];
  const float* W    = (const float*)d_in[2];
  const float* bias = (const float*)d_in[3];
  const float* x0   = (const float*)d_in[4];
  float* out = (float*)d_out;
  int*   wsbar = (int*)d_ws;
  short* shi  = (short*)((char*)d_ws + 2048);
  short* slo  = shi + 8 * 2 * SB_REGION;            // +512 KB
  short* wsWh = slo + 8 * 2 * SB_REGION;            // +512 KB
  short* wsWl = wsWh + 1024 * 1024;                 // +2 MB
  short* rsh  = wsWl + 1024 * 1024;                 // +2 MB
  short* rsl  = rsh + 512 * 1024;                   // +1 MB

  init_kernel<<<dim3(512), dim3(256), 0, stream>>>(x0, shi, slo, wsbar);
  winit_kernel<<<dim3(4096), dim3(256), 0, stream>>>(W, wsWh, wsWl);
  rinit_kernel<<<dim3(2048), dim3(256), 0, stream>>>(R, rsh, rsl);
  hproj_kernel<<<dim3(1024), dim3(256), 0, stream>>>(inp, rsh, rsl, bias, out);
  recur_kernel<<<dim3(128), dim3(512), 0, stream>>>(wsWh, wsWl, out, wsbar, shi, slo);
}